// Round 22
// baseline (113.145 us; speedup 1.0000x reference)
//
#include <hip/hip_runtime.h>
#include <hip/hip_bf16.h>

#define B_ 64
#define J_ 2048
#define K_ 32
#define D_ 16
#define KD 512
#define NCH 256      // j-chunks == grid size (block ch owns j-chunk ch)
#define JCR 8        // j's per chunk

typedef __attribute__((ext_vector_type(8))) short short8v;    // 8 bf16 (4 VGPR)
typedef __attribute__((ext_vector_type(16))) float f32x16;    // 16 f32 acc (32x32)
typedef __attribute__((ext_vector_type(4))) float f32x4v;     // ext-vec float4 (nt ok)

__device__ __forceinline__ float bf2f(unsigned int bits16) {
  unsigned int u = bits16 << 16;
  return __builtin_bit_cast(float, u);
}
// HW packed f32->bf16 pair convert (gfx950; no builtin -- inline asm). lo -> low16.
__device__ __forceinline__ unsigned int cvtpk(float lo, float hi) {
  unsigned int r;
  asm("v_cvt_pk_bf16_f32 %0, %1, %2" : "=v"(r) : "v"(lo), "v"(hi));
  return r;
}
__device__ __forceinline__ f32x16 zero16() {
  f32x16 z;
#pragma unroll
  for (int i = 0; i < 16; ++i) z[i] = 0.f;
  return z;
}
__device__ __forceinline__ f32x4v nt_load4(const float* p) {
  return __builtin_nontemporal_load((const f32x4v*)p);
}
__device__ __forceinline__ void nt_store4(float* p, float a, float b, float c, float d) {
  f32x4v v = {a, b, c, d};
  __builtin_nontemporal_store(v, (f32x4v*)p);
}

// ---------------- k_R0W: iter-0 sweep (c = 1/32) fused with W f32->bf16 conversion
// (r18-proven v2). r21: nt W-loads (streamed once -- keep L2 for WB/spart), and
// dumps the converted x-slice to global XT (bf16, 4 MB) for R1/R2.
__global__ __launch_bounds__(512, 1) void k_R0W(const float* __restrict__ inp,
                                                const float* __restrict__ W,
                                                unsigned short* __restrict__ WB,
                                                unsigned int* __restrict__ XTg,
                                                unsigned int* __restrict__ spart_pk) {
  const int ch = blockIdx.x;
  const int t = threadIdx.x;
  const int wave = t >> 6, lane = t & 63;
  const int hi = lane >> 5, b31 = lane & 31;
  const int j0 = ch * JCR;

  __shared__ unsigned int XT_lds[JCR * 64 * 8];   // 16 KB
  // x-slice -> LDS (r19-proven): 512 threads cover 64 b x 8 jj
  {
    const int b = t >> 3, jj = t & 7;
    const float* src = inp + ((size_t)b * J_ + j0 + jj) * 16;
    const float4 v0 = ((const float4*)src)[0];
    const float4 v1 = ((const float4*)src)[1];
    const float4 v2 = ((const float4*)src)[2];
    const float4 v3 = ((const float4*)src)[3];
    unsigned int* dst = &XT_lds[(jj * 64 + b) * 8];
    dst[0] = cvtpk(v0.x, v0.y); dst[1] = cvtpk(v0.z, v0.w);
    dst[2] = cvtpk(v1.x, v1.y); dst[3] = cvtpk(v1.z, v1.w);
    dst[4] = cvtpk(v2.x, v2.y); dst[5] = cvtpk(v2.z, v2.w);
    dst[6] = cvtpk(v3.x, v3.y); dst[7] = cvtpk(v3.z, v3.w);
  }
  __syncthreads();
  // dump XT slice to global (coalesced; re-read by R1/R2)
  {
    uint4* gbase = (uint4*)(XTg + (size_t)j0 * 512);
    const uint4* lbase = (const uint4*)XT_lds;
    gbase[t] = lbase[t];
    gbase[t + 512] = lbase[t + 512];
  }

  // lane's W row for q: k = 4*wave + 2q + (b31>>4), d = b31&15, i0 = 8hi
  const float* wsrc = W + ((size_t)(4 * wave + (b31 >> 4)) * J_ + j0) * 256 +
                      (b31 & 15) * 16 + 8 * hi;
  unsigned short* wdst = WB + (size_t)j0 * 8192 + (4 * wave + (b31 >> 4)) * 256 +
                         (b31 & 15) * 16 + 8 * hi;
  const size_t qstep = (size_t)2 * J_ * 256;

  f32x16 acc[2][2];
#pragma unroll
  for (int q = 0; q < 2; ++q)
#pragma unroll
    for (int bt = 0; bt < 2; ++bt) acc[q][bt] = zero16();

  f32x4v wc[4];
#pragma unroll
  for (int q = 0; q < 2; ++q) {
    wc[2 * q]     = nt_load4(wsrc + (size_t)q * qstep);
    wc[2 * q + 1] = nt_load4(wsrc + (size_t)q * qstep + 4);
  }

  for (int jj = 0; jj < JCR; ++jj) {
    f32x4v wn[4];
    if (jj + 1 < JCR) {
#pragma unroll
      for (int q = 0; q < 2; ++q) {
        const float* ws2 = wsrc + (size_t)(jj + 1) * 256 + (size_t)q * qstep;
        wn[2 * q] = nt_load4(ws2);
        wn[2 * q + 1] = nt_load4(ws2 + 4);
      }
    }
    const short8v xf0 = __builtin_bit_cast(short8v,
        *(const uint4*)&XT_lds[((size_t)jj * 64 + b31) * 8 + 4 * hi]);
    const short8v xf1 = __builtin_bit_cast(short8v,
        *(const uint4*)&XT_lds[((size_t)jj * 64 + 32 + b31) * 8 + 4 * hi]);
#pragma unroll
    for (int q = 0; q < 2; ++q) {
      uint4 wv;
      wv.x = cvtpk(wc[2 * q][0], wc[2 * q][1]);
      wv.y = cvtpk(wc[2 * q][2], wc[2 * q][3]);
      wv.z = cvtpk(wc[2 * q + 1][0], wc[2 * q + 1][1]);
      wv.w = cvtpk(wc[2 * q + 1][2], wc[2 * q + 1][3]);
      *(uint4*)(wdst + (size_t)jj * 8192 + q * 512) = wv;   // WB side-product (L2-wanted)
      const short8v af = __builtin_bit_cast(short8v, wv);
      acc[q][0] = __builtin_amdgcn_mfma_f32_32x32x16_bf16(af, xf0, acc[q][0], 0, 0, 0);
      acc[q][1] = __builtin_amdgcn_mfma_f32_32x32x16_bf16(af, xf1, acc[q][1], 0, 0, 0);
    }
#pragma unroll
    for (int p = 0; p < 4; ++p) wc[p] = wn[p];
  }

  // spart store, bf16-packed d-pairs (r15 layout), sc = 1/32
  const float sc = 1.f / 32.f;
#pragma unroll
  for (int q = 0; q < 2; ++q) {
#pragma unroll
    for (int bt = 0; bt < 2; ++bt) {
      const int keven = 4 * wave + 2 * q;
      const int b = bt * 32 + b31;
      const float* a = (const float*)&acc[q][bt];
      unsigned int* se = spart_pk + (((size_t)b * NCH + ch) * 32 + keven) * 8 + 2 * hi;
      *(uint2*)se = make_uint2(cvtpk(a[0] * sc, a[1] * sc), cvtpk(a[2] * sc, a[3] * sc));
      *(uint2*)(se + 4) = make_uint2(cvtpk(a[4] * sc, a[5] * sc), cvtpk(a[6] * sc, a[7] * sc));
      unsigned int* so = se + 8;
      *(uint2*)so = make_uint2(cvtpk(a[8] * sc, a[9] * sc), cvtpk(a[10] * sc, a[11] * sc));
      *(uint2*)(so + 4) =
          make_uint2(cvtpk(a[12] * sc, a[13] * sc), cvtpk(a[14] * sc, a[15] * sc));
    }
  }
}

// ---------------- k_R: routing sweep (r15/r18-proven body; x from global XT bf16 with
// depth-1 prefetch). MODE 1: plain. MODE 2: final -- c via padded LDS tile -> outp (nt).
template <int MODE>
__global__ __launch_bounds__(512, 1) void k_R(const unsigned int* __restrict__ XTg,
                                              const unsigned short* __restrict__ WB,
                                              const unsigned short* __restrict__ osB,
                                              unsigned int* __restrict__ spart_pk,
                                              float* __restrict__ outp) {
  const int ch = blockIdx.x;
  const int t = threadIdx.x;
  const int wave = t >> 6, lane = t & 63;
  const int kq = wave & 3, bt = wave >> 2;
  const int hi = lane >> 5, b31 = lane & 31;
  const int b = bt * 32 + b31;
  const int j0 = ch * JCR;

  __shared__ float Sbuf[2 * 4 * 2 * 32];                   // 2 KB
  __shared__ float c_lds[(MODE == 2) ? 32 * 64 * 9 : 4];   // 72 KB (MODE 2)

  // hoisted packed os for k = 8kq .. 8kq+7 (slot s <-> d = (s&3)+4hi+8*(s>>2))
  uint4 os_pk[8];
  {
    const unsigned short* osb = osB + ((size_t)bt * 64 + lane) * 8 + (size_t)(8 * kq) * 1024;
#pragma unroll
    for (int kk = 0; kk < 8; ++kk) os_pk[kk] = *(const uint4*)(osb + (size_t)kk * 1024);
  }

  float acc[4][16];
#pragma unroll
  for (int q = 0; q < 4; ++q)
#pragma unroll
    for (int s = 0; s < 16; ++s) acc[q][s] = 0.f;

  const unsigned short* waBase =
      WB + (size_t)j0 * 8192 + (b31 >> 4) * 256 + (b31 & 15) * 16 + 8 * hi + (size_t)kq * 2048;
  const unsigned int* xBase = XTg + (size_t)j0 * 512 + b * 8 + 4 * hi;

  uint4 a_cur[4], b_cur;
#pragma unroll
  for (int q = 0; q < 4; ++q) a_cur[q] = *(const uint4*)(waBase + q * 512);
  b_cur = *(const uint4*)xBase;

  for (int jj = 0; jj < JCR; ++jj) {
    uint4 a_nxt[4], b_nxt;
    if (jj + 1 < JCR) {
#pragma unroll
      for (int q = 0; q < 4; ++q)
        a_nxt[q] = *(const uint4*)(waBase + (size_t)(jj + 1) * 8192 + q * 512);
      b_nxt = *(const uint4*)(xBase + (size_t)(jj + 1) * 512);
    }
    const short8v xf = __builtin_bit_cast(short8v, b_cur);

    f32x16 u[4];
#pragma unroll
    for (int q = 0; q < 4; ++q)
      u[q] = __builtin_amdgcn_mfma_f32_32x32x16_bf16(
          __builtin_bit_cast(short8v, a_cur[q]), xf, zero16(), 0, 0, 0);

    float ee[4], eo[4];
    float Sp = 0.f;
#pragma unroll
    for (int q = 0; q < 4; ++q) {
      const unsigned int* o0 = (const unsigned int*)&os_pk[2 * q];
      const unsigned int* o1 = (const unsigned int*)&os_pk[2 * q + 1];
      float pe = 0.f, po = 0.f;
#pragma unroll
      for (int s = 0; s < 8; ++s) {
        const unsigned int w0 = o0[s >> 1], w1 = o1[s >> 1];
        pe = fmaf(u[q][s], bf2f((s & 1) ? (w0 >> 16) : (w0 & 0xffffu)), pe);
        po = fmaf(u[q][8 + s], bf2f((s & 1) ? (w1 >> 16) : (w1 & 0xffffu)), po);
      }
      pe += __shfl_xor(pe, 32);      // partner hi-half -> full dot over d
      po += __shfl_xor(po, 32);
      // logits O(+-8): skip max-subtraction (shift-invariant; validated r1-r20)
      ee[q] = __expf(pe);
      eo[q] = __expf(po);
      Sp += ee[q] + eo[q];
    }
    // cross-wave S reduction over the 4 kq waves (same bt); dbuf on jj parity
    if (hi == 0) Sbuf[((jj & 1) * 8 + kq * 2 + bt) * 32 + b31] = Sp;
    __syncthreads();
    const int sb = (jj & 1) * 8;
    const float S = Sbuf[(sb + 0 * 2 + bt) * 32 + b31] + Sbuf[(sb + 1 * 2 + bt) * 32 + b31] +
                    Sbuf[(sb + 2 * 2 + bt) * 32 + b31] + Sbuf[(sb + 3 * 2 + bt) * 32 + b31];
    const float rS = __builtin_amdgcn_rcpf(S);
#pragma unroll
    for (int q = 0; q < 4; ++q) {
      const float ce = ee[q] * rS, co = eo[q] * rS;
#pragma unroll
      for (int s = 0; s < 8; ++s) {
        acc[q][s] = fmaf(ce, u[q][s], acc[q][s]);
        acc[q][8 + s] = fmaf(co, u[q][8 + s], acc[q][8 + s]);
      }
      if constexpr (MODE == 2) {
        if (hi == 0) {
          const int k0 = 8 * kq + 2 * q;
          c_lds[((k0)*64 + b) * 9 + jj] = ce;       // pad-9: conflict-free
          c_lds[((k0 + 1) * 64 + b) * 9 + jj] = co;
        }
      }
    }
#pragma unroll
    for (int q = 0; q < 4; ++q) a_cur[q] = a_nxt[q];
    b_cur = b_nxt;
  }

  // spart store, bf16-packed d-pairs
#pragma unroll
  for (int q = 0; q < 4; ++q) {
    const int keven = 8 * kq + 2 * q;
    unsigned int* se = spart_pk + (((size_t)b * NCH + ch) * 32 + keven) * 8 + 2 * hi;
    *(uint2*)se = make_uint2(cvtpk(acc[q][0], acc[q][1]), cvtpk(acc[q][2], acc[q][3]));
    *(uint2*)(se + 4) = make_uint2(cvtpk(acc[q][4], acc[q][5]), cvtpk(acc[q][6], acc[q][7]));
    unsigned int* so = se + 8;
    *(uint2*)so = make_uint2(cvtpk(acc[q][8], acc[q][9]), cvtpk(acc[q][10], acc[q][11]));
    *(uint2*)(so + 4) =
        make_uint2(cvtpk(acc[q][12], acc[q][13]), cvtpk(acc[q][14], acc[q][15]));
  }

  if constexpr (MODE == 2) {
    __syncthreads();
    // c transpose out (nt stores: never re-read): row r = k*64+b; 8 j's contiguous
#pragma unroll
    for (int m = 0; m < 4; ++m) {
      const int r = m * 512 + t;
      const int k = r >> 6, bb = r & 63;
      const float* cr = &c_lds[r * 9];
      float* orow = outp + ((size_t)bb * K_ + k) * 2064 + 16 + j0;
      nt_store4(orow, cr[0], cr[1], cr[2], cr[3]);
      nt_store4(orow + 4, cr[4], cr[5], cr[6], cr[7]);
    }
  }
}

// ---------------- squash: reduce packed spart (depth NCH) -> s, squash -> o.
// Wave per (b,k). Lane: h = d-pair (d = 2h, 2h+1), pg = lane>>3 (8 p-groups).
__global__ __launch_bounds__(256) void k_squash(const unsigned int* __restrict__ spart_pk,
                                                float* __restrict__ osum,
                                                unsigned short* __restrict__ osB,
                                                float* __restrict__ outp,
                                                int first, int final_) {
  const int t = threadIdx.x;
  const int wave = t >> 6, lane = t & 63;
  const int gw = blockIdx.x * 4 + wave;   // 0..B_*K_-1
  const int b = gw >> 5, k = gw & 31;
  const int h = lane & 7, pg = lane >> 3;
  float s0 = 0.f, s1 = 0.f;
#pragma unroll 8
  for (int p = pg; p < NCH; p += 8) {
    const unsigned int v = spart_pk[(((size_t)b * NCH + p) * 32 + k) * 8 + h];
    s0 += bf2f(v & 0xffffu);
    s1 += bf2f(v >> 16);
  }
  s0 += __shfl_xor(s0, 8);  s1 += __shfl_xor(s1, 8);
  s0 += __shfl_xor(s0, 16); s1 += __shfl_xor(s1, 16);
  s0 += __shfl_xor(s0, 32); s1 += __shfl_xor(s1, 32);
  float ss = s0 * s0 + s1 * s1;
  ss += __shfl_xor(ss, 1); ss += __shfl_xor(ss, 2); ss += __shfl_xor(ss, 4);
  const float scale = (ss / (1.f + ss)) * rsqrtf(ss + 1e-7f);
  const float ov0 = scale * s0, ov1 = scale * s1;
  if (final_) {
    if (pg == 0)
      *(float2*)(outp + ((size_t)b * K_ + k) * 2064 + 2 * h) = make_float2(ov0, ov1);
  } else {
    if (pg == 0) {
      float2 prev = make_float2(0.f, 0.f);
      if (!first) prev = *(const float2*)(osum + b * KD + k * 16 + 2 * h);
      const float ns0 = prev.x + ov0, ns1 = prev.y + ov1;
      *(float2*)(osum + b * KD + k * 16 + 2 * h) = make_float2(ns0, ns1);
      const int d0 = 2 * h;
      const int hi0 = (d0 >> 2) & 1;
      const int slot0 = (d0 & 3) + ((d0 >> 3) << 2);
      *(unsigned int*)(osB + (((size_t)k * 2 + (b >> 5)) * 64 + hi0 * 32 + (b & 31)) * 8 +
                       slot0) = cvtpk(ns0, ns1);
    }
  }
}

extern "C" void kernel_launch(void* const* d_in, const int* in_sizes, int n_in,
                              void* d_out, int out_size, void* d_ws, size_t ws_size,
                              hipStream_t stream) {
  const float* inp = (const float*)d_in[0];   // [64,2048,16]
  const float* W   = (const float*)d_in[1];   // [32,2048,16,16]
  float* outp = (float*)d_out;                // [64,32,2064]
  char* ws = (char*)d_ws;
  // ws: WB 32M @0 | spart_pk 16M @32M | osum 128K @48M | osB 64K | XTg 4M
  unsigned short* WB = (unsigned short*)ws;
  unsigned int* spart_pk = (unsigned int*)(ws + (size_t)33554432);
  float* osum = (float*)(ws + (size_t)50331648);
  unsigned short* osB = (unsigned short*)(ws + (size_t)50331648 + 131072);
  unsigned int* XTg = (unsigned int*)(ws + (size_t)50331648 + 131072 + 65536);

  // iter 0: c = 1/32, fused with x conversion (dumps XTg) and W->bf16 (writes WB)
  k_R0W<<<NCH, 512, 0, stream>>>(inp, W, WB, XTg, spart_pk);
  k_squash<<<B_ * K_ / 4, 256, 0, stream>>>(spart_pk, osum, osB, outp, 1, 0);
  // iter 1
  k_R<1><<<NCH, 512, 0, stream>>>(XTg, WB, osB, spart_pk, nullptr);
  k_squash<<<B_ * K_ / 4, 256, 0, stream>>>(spart_pk, osum, osB, outp, 0, 0);
  // iter 2 (final): c -> outp via LDS transpose (nt stores)
  k_R<2><<<NCH, 512, 0, stream>>>(XTg, WB, osB, spart_pk, outp);
  k_squash<<<B_ * K_ / 4, 256, 0, stream>>>(spart_pk, osum, osB, outp, 0, 1);
}

// Round 23
// 91.171 us; speedup vs baseline: 1.2410x; 1.2410x over previous
//
#include <hip/hip_runtime.h>
#include <hip/hip_bf16.h>

#define B_ 64
#define J_ 2048
#define K_ 32
#define D_ 16
#define KD 512
#define NCH 256      // j-chunks == grid size (block ch owns j-chunk ch)
#define JCR 8        // j's per chunk

typedef __attribute__((ext_vector_type(8))) short short8v;    // 8 bf16 (4 VGPR)
typedef __attribute__((ext_vector_type(16))) float f32x16;    // 16 f32 acc (32x32)
typedef __attribute__((ext_vector_type(4))) float f32x4v;     // ext-vec float4 (nt ok)

__device__ __forceinline__ float bf2f(unsigned int bits16) {
  unsigned int u = bits16 << 16;
  return __builtin_bit_cast(float, u);
}
// HW packed f32->bf16 pair convert (gfx950; no builtin -- inline asm). lo -> low16.
__device__ __forceinline__ unsigned int cvtpk(float lo, float hi) {
  unsigned int r;
  asm("v_cvt_pk_bf16_f32 %0, %1, %2" : "=v"(r) : "v"(lo), "v"(hi));
  return r;
}
__device__ __forceinline__ f32x16 zero16() {
  f32x16 z;
#pragma unroll
  for (int i = 0; i < 16; ++i) z[i] = 0.f;
  return z;
}
__device__ __forceinline__ f32x4v nt_load4(const float* p) {
  return __builtin_nontemporal_load((const f32x4v*)p);
}

// ---- per-block x-slice conversion into LDS (r19/r20-proven): 512 threads cover
// 64 b x 8 jj; reads 32KB f32 coalesced, writes XT_lds[jj][b][8 dwords].
__device__ __forceinline__ void x_to_lds(const float* __restrict__ inp,
                                         unsigned int* __restrict__ XT_lds,
                                         int j0, int t) {
  const int b = t >> 3, jj = t & 7;
  const float* src = inp + ((size_t)b * J_ + j0 + jj) * 16;
  const float4 v0 = ((const float4*)src)[0];
  const float4 v1 = ((const float4*)src)[1];
  const float4 v2 = ((const float4*)src)[2];
  const float4 v3 = ((const float4*)src)[3];
  unsigned int* dst = &XT_lds[(jj * 64 + b) * 8];
  dst[0] = cvtpk(v0.x, v0.y); dst[1] = cvtpk(v0.z, v0.w);
  dst[2] = cvtpk(v1.x, v1.y); dst[3] = cvtpk(v1.z, v1.w);
  dst[4] = cvtpk(v2.x, v2.y); dst[5] = cvtpk(v2.z, v2.w);
  dst[6] = cvtpk(v3.x, v3.y); dst[7] = cvtpk(v3.z, v3.w);
}

// ---------------- k_R0W: iter-0 sweep (c = 1/32) fused with W f32->bf16 conversion
// (r18/r20-proven v2 body; x from LDS). r23: nt W-loads (W streamed exactly once --
// keep L2 for WB/spart). Wave = k-octant covering both b-tiles. Grid 256 = 1 block/CU.
__global__ __launch_bounds__(512, 1) void k_R0W(const float* __restrict__ inp,
                                                const float* __restrict__ W,
                                                unsigned short* __restrict__ WB,
                                                unsigned int* __restrict__ spart_pk) {
  const int ch = blockIdx.x;
  const int t = threadIdx.x;
  const int wave = t >> 6, lane = t & 63;
  const int hi = lane >> 5, b31 = lane & 31;
  const int j0 = ch * JCR;

  __shared__ unsigned int XT_lds[JCR * 64 * 8];   // 16 KB
  x_to_lds(inp, XT_lds, j0, t);
  __syncthreads();

  // lane's W row for q: k = 4*wave + 2q + (b31>>4), d = b31&15, i0 = 8hi
  const float* wsrc = W + ((size_t)(4 * wave + (b31 >> 4)) * J_ + j0) * 256 +
                      (b31 & 15) * 16 + 8 * hi;
  unsigned short* wdst = WB + (size_t)j0 * 8192 + (4 * wave + (b31 >> 4)) * 256 +
                         (b31 & 15) * 16 + 8 * hi;
  const size_t qstep = (size_t)2 * J_ * 256;

  f32x16 acc[2][2];
#pragma unroll
  for (int q = 0; q < 2; ++q)
#pragma unroll
    for (int bt = 0; bt < 2; ++bt) acc[q][bt] = zero16();

  f32x4v wc[4];
#pragma unroll
  for (int q = 0; q < 2; ++q) {
    wc[2 * q]     = nt_load4(wsrc + (size_t)q * qstep);
    wc[2 * q + 1] = nt_load4(wsrc + (size_t)q * qstep + 4);
  }

  for (int jj = 0; jj < JCR; ++jj) {
    f32x4v wn[4];
    if (jj + 1 < JCR) {
#pragma unroll
      for (int q = 0; q < 2; ++q) {
        const float* ws2 = wsrc + (size_t)(jj + 1) * 256 + (size_t)q * qstep;
        wn[2 * q] = nt_load4(ws2);
        wn[2 * q + 1] = nt_load4(ws2 + 4);
      }
    }
    const short8v xf0 = __builtin_bit_cast(short8v,
        *(const uint4*)&XT_lds[((size_t)jj * 64 + b31) * 8 + 4 * hi]);
    const short8v xf1 = __builtin_bit_cast(short8v,
        *(const uint4*)&XT_lds[((size_t)jj * 64 + 32 + b31) * 8 + 4 * hi]);
#pragma unroll
    for (int q = 0; q < 2; ++q) {
      uint4 wv;
      wv.x = cvtpk(wc[2 * q][0], wc[2 * q][1]);
      wv.y = cvtpk(wc[2 * q][2], wc[2 * q][3]);
      wv.z = cvtpk(wc[2 * q + 1][0], wc[2 * q + 1][1]);
      wv.w = cvtpk(wc[2 * q + 1][2], wc[2 * q + 1][3]);
      *(uint4*)(wdst + (size_t)jj * 8192 + q * 512) = wv;   // WB side-product
      const short8v af = __builtin_bit_cast(short8v, wv);
      acc[q][0] = __builtin_amdgcn_mfma_f32_32x32x16_bf16(af, xf0, acc[q][0], 0, 0, 0);
      acc[q][1] = __builtin_amdgcn_mfma_f32_32x32x16_bf16(af, xf1, acc[q][1], 0, 0, 0);
    }
#pragma unroll
    for (int p = 0; p < 4; ++p) wc[p] = wn[p];
  }

  // spart store, bf16-packed d-pairs (r15 layout), sc = 1/32
  const float sc = 1.f / 32.f;
#pragma unroll
  for (int q = 0; q < 2; ++q) {
#pragma unroll
    for (int bt = 0; bt < 2; ++bt) {
      const int keven = 4 * wave + 2 * q;
      const int b = bt * 32 + b31;
      const float* a = (const float*)&acc[q][bt];
      unsigned int* se = spart_pk + (((size_t)b * NCH + ch) * 32 + keven) * 8 + 2 * hi;
      *(uint2*)se = make_uint2(cvtpk(a[0] * sc, a[1] * sc), cvtpk(a[2] * sc, a[3] * sc));
      *(uint2*)(se + 4) = make_uint2(cvtpk(a[4] * sc, a[5] * sc), cvtpk(a[6] * sc, a[7] * sc));
      unsigned int* so = se + 8;
      *(uint2*)so = make_uint2(cvtpk(a[8] * sc, a[9] * sc), cvtpk(a[10] * sc, a[11] * sc));
      *(uint2*)(so + 4) =
          make_uint2(cvtpk(a[12] * sc, a[13] * sc), cvtpk(a[14] * sc, a[15] * sc));
    }
  }
}

// ---------------- k_R: routing sweep (r20-proven body; x from LDS).
// MODE 1: plain sweep. MODE 2: final -- c via padded LDS tile straight into outp.
template <int MODE>
__global__ __launch_bounds__(512, 1) void k_R(const float* __restrict__ inp,
                                              const unsigned short* __restrict__ WB,
                                              const unsigned short* __restrict__ osB,
                                              unsigned int* __restrict__ spart_pk,
                                              float* __restrict__ outp) {
  const int ch = blockIdx.x;
  const int t = threadIdx.x;
  const int wave = t >> 6, lane = t & 63;
  const int kq = wave & 3, bt = wave >> 2;
  const int hi = lane >> 5, b31 = lane & 31;
  const int b = bt * 32 + b31;
  const int j0 = ch * JCR;

  __shared__ unsigned int XT_lds[JCR * 64 * 8];            // 16 KB
  __shared__ float Sbuf[2 * 4 * 2 * 32];                   // 2 KB
  __shared__ float c_lds[(MODE == 2) ? 32 * 64 * 9 : 4];   // 72 KB (MODE 2)

  x_to_lds(inp, XT_lds, j0, t);

  // hoisted packed os for k = 8kq .. 8kq+7 (slot s <-> d = (s&3)+4hi+8*(s>>2))
  uint4 os_pk[8];
  {
    const unsigned short* osb = osB + ((size_t)bt * 64 + lane) * 8 + (size_t)(8 * kq) * 1024;
#pragma unroll
    for (int kk = 0; kk < 8; ++kk) os_pk[kk] = *(const uint4*)(osb + (size_t)kk * 1024);
  }

  float acc[4][16];
#pragma unroll
  for (int q = 0; q < 4; ++q)
#pragma unroll
    for (int s = 0; s < 16; ++s) acc[q][s] = 0.f;

  const unsigned short* waBase =
      WB + (size_t)j0 * 8192 + (b31 >> 4) * 256 + (b31 & 15) * 16 + 8 * hi + (size_t)kq * 2048;

  uint4 a_cur[4];
#pragma unroll
  for (int q = 0; q < 4; ++q) a_cur[q] = *(const uint4*)(waBase + q * 512);
  __syncthreads();   // XT_lds ready

  for (int jj = 0; jj < JCR; ++jj) {
    uint4 a_nxt[4];
    if (jj + 1 < JCR) {
#pragma unroll
      for (int q = 0; q < 4; ++q)
        a_nxt[q] = *(const uint4*)(waBase + (size_t)(jj + 1) * 8192 + q * 512);
    }
    const short8v xf = __builtin_bit_cast(short8v,
        *(const uint4*)&XT_lds[((size_t)jj * 64 + b) * 8 + 4 * hi]);

    f32x16 u[4];
#pragma unroll
    for (int q = 0; q < 4; ++q)
      u[q] = __builtin_amdgcn_mfma_f32_32x32x16_bf16(
          __builtin_bit_cast(short8v, a_cur[q]), xf, zero16(), 0, 0, 0);

    float ee[4], eo[4];
    float Sp = 0.f;
#pragma unroll
    for (int q = 0; q < 4; ++q) {
      const unsigned int* o0 = (const unsigned int*)&os_pk[2 * q];
      const unsigned int* o1 = (const unsigned int*)&os_pk[2 * q + 1];
      float pe = 0.f, po = 0.f;
#pragma unroll
      for (int s = 0; s < 8; ++s) {
        const unsigned int w0 = o0[s >> 1], w1 = o1[s >> 1];
        pe = fmaf(u[q][s], bf2f((s & 1) ? (w0 >> 16) : (w0 & 0xffffu)), pe);
        po = fmaf(u[q][8 + s], bf2f((s & 1) ? (w1 >> 16) : (w1 & 0xffffu)), po);
      }
      pe += __shfl_xor(pe, 32);      // partner hi-half -> full dot over d
      po += __shfl_xor(po, 32);
      // logits O(+-8): skip max-subtraction (shift-invariant; validated r1-r22)
      ee[q] = __expf(pe);
      eo[q] = __expf(po);
      Sp += ee[q] + eo[q];
    }
    // cross-wave S reduction over the 4 kq waves (same bt); dbuf on jj parity
    if (hi == 0) Sbuf[((jj & 1) * 8 + kq * 2 + bt) * 32 + b31] = Sp;
    __syncthreads();
    const int sb = (jj & 1) * 8;
    const float S = Sbuf[(sb + 0 * 2 + bt) * 32 + b31] + Sbuf[(sb + 1 * 2 + bt) * 32 + b31] +
                    Sbuf[(sb + 2 * 2 + bt) * 32 + b31] + Sbuf[(sb + 3 * 2 + bt) * 32 + b31];
    const float rS = __builtin_amdgcn_rcpf(S);
#pragma unroll
    for (int q = 0; q < 4; ++q) {
      const float ce = ee[q] * rS, co = eo[q] * rS;
#pragma unroll
      for (int s = 0; s < 8; ++s) {
        acc[q][s] = fmaf(ce, u[q][s], acc[q][s]);
        acc[q][8 + s] = fmaf(co, u[q][8 + s], acc[q][8 + s]);
      }
      if constexpr (MODE == 2) {
        if (hi == 0) {
          const int k0 = 8 * kq + 2 * q;
          c_lds[((k0)*64 + b) * 9 + jj] = ce;       // pad-9: conflict-free
          c_lds[((k0 + 1) * 64 + b) * 9 + jj] = co;
        }
      }
    }
#pragma unroll
    for (int q = 0; q < 4; ++q) a_cur[q] = a_nxt[q];
  }

  // spart store, bf16-packed d-pairs
#pragma unroll
  for (int q = 0; q < 4; ++q) {
    const int keven = 8 * kq + 2 * q;
    unsigned int* se = spart_pk + (((size_t)b * NCH + ch) * 32 + keven) * 8 + 2 * hi;
    *(uint2*)se = make_uint2(cvtpk(acc[q][0], acc[q][1]), cvtpk(acc[q][2], acc[q][3]));
    *(uint2*)(se + 4) = make_uint2(cvtpk(acc[q][4], acc[q][5]), cvtpk(acc[q][6], acc[q][7]));
    unsigned int* so = se + 8;
    *(uint2*)so = make_uint2(cvtpk(acc[q][8], acc[q][9]), cvtpk(acc[q][10], acc[q][11]));
    *(uint2*)(so + 4) =
        make_uint2(cvtpk(acc[q][12], acc[q][13]), cvtpk(acc[q][14], acc[q][15]));
  }

  if constexpr (MODE == 2) {
    __syncthreads();
    // c transpose out: row r = k*64+b; 8 j's contiguous at outp[b][k][16+j0..]
#pragma unroll
    for (int m = 0; m < 4; ++m) {
      const int r = m * 512 + t;
      const int k = r >> 6, bb = r & 63;
      const float* cr = &c_lds[r * 9];
      float* orow = outp + ((size_t)bb * K_ + k) * 2064 + 16 + j0;
      *(float4*)orow = make_float4(cr[0], cr[1], cr[2], cr[3]);
      *(float4*)(orow + 4) = make_float4(cr[4], cr[5], cr[6], cr[7]);
    }
  }
}

// ---------------- squash: reduce packed spart (depth NCH) -> s, squash -> o.
// Wave per (b,k). Lane: h = d-pair (d = 2h, 2h+1), pg = lane>>3 (8 p-groups).
__global__ __launch_bounds__(256) void k_squash(const unsigned int* __restrict__ spart_pk,
                                                float* __restrict__ osum,
                                                unsigned short* __restrict__ osB,
                                                float* __restrict__ outp,
                                                int first, int final_) {
  const int t = threadIdx.x;
  const int wave = t >> 6, lane = t & 63;
  const int gw = blockIdx.x * 4 + wave;   // 0..B_*K_-1
  const int b = gw >> 5, k = gw & 31;
  const int h = lane & 7, pg = lane >> 3;
  float s0 = 0.f, s1 = 0.f;
#pragma unroll 8
  for (int p = pg; p < NCH; p += 8) {
    const unsigned int v = spart_pk[(((size_t)b * NCH + p) * 32 + k) * 8 + h];
    s0 += bf2f(v & 0xffffu);
    s1 += bf2f(v >> 16);
  }
  s0 += __shfl_xor(s0, 8);  s1 += __shfl_xor(s1, 8);
  s0 += __shfl_xor(s0, 16); s1 += __shfl_xor(s1, 16);
  s0 += __shfl_xor(s0, 32); s1 += __shfl_xor(s1, 32);
  float ss = s0 * s0 + s1 * s1;
  ss += __shfl_xor(ss, 1); ss += __shfl_xor(ss, 2); ss += __shfl_xor(ss, 4);
  const float scale = (ss / (1.f + ss)) * rsqrtf(ss + 1e-7f);
  const float ov0 = scale * s0, ov1 = scale * s1;
  if (final_) {
    if (pg == 0)
      *(float2*)(outp + ((size_t)b * K_ + k) * 2064 + 2 * h) = make_float2(ov0, ov1);
  } else {
    if (pg == 0) {
      float2 prev = make_float2(0.f, 0.f);
      if (!first) prev = *(const float2*)(osum + b * KD + k * 16 + 2 * h);
      const float ns0 = prev.x + ov0, ns1 = prev.y + ov1;
      *(float2*)(osum + b * KD + k * 16 + 2 * h) = make_float2(ns0, ns1);
      const int d0 = 2 * h;
      const int hi0 = (d0 >> 2) & 1;
      const int slot0 = (d0 & 3) + ((d0 >> 3) << 2);
      *(unsigned int*)(osB + (((size_t)k * 2 + (b >> 5)) * 64 + hi0 * 32 + (b & 31)) * 8 +
                       slot0) = cvtpk(ns0, ns1);
    }
  }
}

extern "C" void kernel_launch(void* const* d_in, const int* in_sizes, int n_in,
                              void* d_out, int out_size, void* d_ws, size_t ws_size,
                              hipStream_t stream) {
  const float* inp = (const float*)d_in[0];   // [64,2048,16]
  const float* W   = (const float*)d_in[1];   // [32,2048,16,16]
  float* outp = (float*)d_out;                // [64,32,2064]
  char* ws = (char*)d_ws;
  // ws: WB 32M @0 | spart_pk 16M @32M | osum 128K @48M | osB 64K
  unsigned short* WB = (unsigned short*)ws;
  unsigned int* spart_pk = (unsigned int*)(ws + (size_t)33554432);
  float* osum = (float*)(ws + (size_t)33554432 + 16777216);
  unsigned short* osB = (unsigned short*)(ws + (size_t)33554432 + 16777216 + 131072);

  // iter 0: c = 1/32, fused with x->LDS conversion and W->bf16 (nt W loads; writes WB)
  k_R0W<<<NCH, 512, 0, stream>>>(inp, W, WB, spart_pk);
  k_squash<<<B_ * K_ / 4, 256, 0, stream>>>(spart_pk, osum, osB, outp, 1, 0);
  // iter 1
  k_R<1><<<NCH, 512, 0, stream>>>(inp, WB, osB, spart_pk, nullptr);
  k_squash<<<B_ * K_ / 4, 256, 0, stream>>>(spart_pk, osum, osB, outp, 0, 0);
  // iter 2 (final): c -> outp via LDS transpose
  k_R<2><<<NCH, 512, 0, stream>>>(inp, WB, osB, spart_pk, outp);
  k_squash<<<B_ * K_ / 4, 256, 0, stream>>>(spart_pk, osum, osB, outp, 0, 1);
}

// Round 24
// 82.927 us; speedup vs baseline: 1.3644x; 1.0994x over previous
//
#include <hip/hip_runtime.h>
#include <hip/hip_bf16.h>

#define B_ 64
#define J_ 2048
#define K_ 32
#define D_ 16
#define KD 512
#define NCH 256      // j-chunks == grid size (block ch owns j-chunk ch)
#define JCR 8        // j's per chunk

typedef __attribute__((ext_vector_type(8))) short short8v;    // 8 bf16 (4 VGPR)
typedef __attribute__((ext_vector_type(16))) float f32x16;    // 16 f32 acc (32x32)

__device__ __forceinline__ float bf2f(unsigned int bits16) {
  unsigned int u = bits16 << 16;
  return __builtin_bit_cast(float, u);
}
// HW packed f32->bf16 pair convert (gfx950; no builtin -- inline asm). lo -> low16.
__device__ __forceinline__ unsigned int cvtpk(float lo, float hi) {
  unsigned int r;
  asm("v_cvt_pk_bf16_f32 %0, %1, %2" : "=v"(r) : "v"(lo), "v"(hi));
  return r;
}
__device__ __forceinline__ f32x16 zero16() {
  f32x16 z;
#pragma unroll
  for (int i = 0; i < 16; ++i) z[i] = 0.f;
  return z;
}

// ---- per-block x-slice conversion into LDS (r19/r20-proven): 512 threads cover
// 64 b x 8 jj; reads 32KB f32 coalesced, writes XT_lds[jj][b][8 dwords].
__device__ __forceinline__ void x_to_lds(const float* __restrict__ inp,
                                         unsigned int* __restrict__ XT_lds,
                                         int j0, int t) {
  const int b = t >> 3, jj = t & 7;
  const float* src = inp + ((size_t)b * J_ + j0 + jj) * 16;
  const float4 v0 = ((const float4*)src)[0];
  const float4 v1 = ((const float4*)src)[1];
  const float4 v2 = ((const float4*)src)[2];
  const float4 v3 = ((const float4*)src)[3];
  unsigned int* dst = &XT_lds[(jj * 64 + b) * 8];
  dst[0] = cvtpk(v0.x, v0.y); dst[1] = cvtpk(v0.z, v0.w);
  dst[2] = cvtpk(v1.x, v1.y); dst[3] = cvtpk(v1.z, v1.w);
  dst[4] = cvtpk(v2.x, v2.y); dst[5] = cvtpk(v2.z, v2.w);
  dst[6] = cvtpk(v3.x, v3.y); dst[7] = cvtpk(v3.z, v3.w);
}

// ---------------- k_R0W: iter-0 sweep (c = 1/32) fused with W f32->bf16 conversion
// (r18-proven v2 body; x from LDS per r19 phase 0/1 -- no prepX, no XT buffer).
// Wave = k-octant covering both b-tiles: W read exactly once. Grid 256 = 1 block/CU.
__global__ __launch_bounds__(512, 1) void k_R0W(const float* __restrict__ inp,
                                                const float* __restrict__ W,
                                                unsigned short* __restrict__ WB,
                                                unsigned int* __restrict__ spart_pk) {
  const int ch = blockIdx.x;
  const int t = threadIdx.x;
  const int wave = t >> 6, lane = t & 63;
  const int hi = lane >> 5, b31 = lane & 31;
  const int j0 = ch * JCR;

  __shared__ unsigned int XT_lds[JCR * 64 * 8];   // 16 KB
  x_to_lds(inp, XT_lds, j0, t);
  __syncthreads();

  // lane's W row for q: k = 4*wave + 2q + (b31>>4), d = b31&15, i0 = 8hi
  const float* wsrc = W + ((size_t)(4 * wave + (b31 >> 4)) * J_ + j0) * 256 +
                      (b31 & 15) * 16 + 8 * hi;
  unsigned short* wdst = WB + (size_t)j0 * 8192 + (4 * wave + (b31 >> 4)) * 256 +
                         (b31 & 15) * 16 + 8 * hi;
  const size_t qstep = (size_t)2 * J_ * 256;

  f32x16 acc[2][2];
#pragma unroll
  for (int q = 0; q < 2; ++q)
#pragma unroll
    for (int bt = 0; bt < 2; ++bt) acc[q][bt] = zero16();

  float4 wc[4];
#pragma unroll
  for (int q = 0; q < 2; ++q) {
    wc[2 * q]     = *(const float4*)(wsrc + (size_t)q * qstep);
    wc[2 * q + 1] = *(const float4*)(wsrc + (size_t)q * qstep + 4);
  }

  for (int jj = 0; jj < JCR; ++jj) {
    float4 wn[4];
    if (jj + 1 < JCR) {
#pragma unroll
      for (int q = 0; q < 2; ++q) {
        const float* ws2 = wsrc + (size_t)(jj + 1) * 256 + (size_t)q * qstep;
        wn[2 * q] = *(const float4*)ws2;
        wn[2 * q + 1] = *(const float4*)(ws2 + 4);
      }
    }
    const short8v xf0 = __builtin_bit_cast(short8v,
        *(const uint4*)&XT_lds[((size_t)jj * 64 + b31) * 8 + 4 * hi]);
    const short8v xf1 = __builtin_bit_cast(short8v,
        *(const uint4*)&XT_lds[((size_t)jj * 64 + 32 + b31) * 8 + 4 * hi]);
#pragma unroll
    for (int q = 0; q < 2; ++q) {
      uint4 wv;
      wv.x = cvtpk(wc[2 * q].x, wc[2 * q].y);
      wv.y = cvtpk(wc[2 * q].z, wc[2 * q].w);
      wv.z = cvtpk(wc[2 * q + 1].x, wc[2 * q + 1].y);
      wv.w = cvtpk(wc[2 * q + 1].z, wc[2 * q + 1].w);
      *(uint4*)(wdst + (size_t)jj * 8192 + q * 512) = wv;   // WB side-product
      const short8v af = __builtin_bit_cast(short8v, wv);
      acc[q][0] = __builtin_amdgcn_mfma_f32_32x32x16_bf16(af, xf0, acc[q][0], 0, 0, 0);
      acc[q][1] = __builtin_amdgcn_mfma_f32_32x32x16_bf16(af, xf1, acc[q][1], 0, 0, 0);
    }
#pragma unroll
    for (int p = 0; p < 4; ++p) wc[p] = wn[p];
  }

  // spart store, bf16-packed d-pairs (r15 layout), sc = 1/32
  const float sc = 1.f / 32.f;
#pragma unroll
  for (int q = 0; q < 2; ++q) {
#pragma unroll
    for (int bt = 0; bt < 2; ++bt) {
      const int keven = 4 * wave + 2 * q;
      const int b = bt * 32 + b31;
      const float* a = (const float*)&acc[q][bt];
      unsigned int* se = spart_pk + (((size_t)b * NCH + ch) * 32 + keven) * 8 + 2 * hi;
      *(uint2*)se = make_uint2(cvtpk(a[0] * sc, a[1] * sc), cvtpk(a[2] * sc, a[3] * sc));
      *(uint2*)(se + 4) = make_uint2(cvtpk(a[4] * sc, a[5] * sc), cvtpk(a[6] * sc, a[7] * sc));
      unsigned int* so = se + 8;
      *(uint2*)so = make_uint2(cvtpk(a[8] * sc, a[9] * sc), cvtpk(a[10] * sc, a[11] * sc));
      *(uint2*)(so + 4) =
          make_uint2(cvtpk(a[12] * sc, a[13] * sc), cvtpk(a[14] * sc, a[15] * sc));
    }
  }
}

// ---------------- k_R: routing sweep (r18-proven body; x from LDS per r19).
// MODE 1: plain sweep. MODE 2: final -- c via padded LDS tile straight into outp.
template <int MODE>
__global__ __launch_bounds__(512, 1) void k_R(const float* __restrict__ inp,
                                              const unsigned short* __restrict__ WB,
                                              const unsigned short* __restrict__ osB,
                                              unsigned int* __restrict__ spart_pk,
                                              float* __restrict__ outp) {
  const int ch = blockIdx.x;
  const int t = threadIdx.x;
  const int wave = t >> 6, lane = t & 63;
  const int kq = wave & 3, bt = wave >> 2;
  const int hi = lane >> 5, b31 = lane & 31;
  const int b = bt * 32 + b31;
  const int j0 = ch * JCR;

  __shared__ unsigned int XT_lds[JCR * 64 * 8];            // 16 KB
  __shared__ float Sbuf[2 * 4 * 2 * 32];                   // 2 KB
  __shared__ float c_lds[(MODE == 2) ? 32 * 64 * 9 : 4];   // 72 KB (MODE 2)

  x_to_lds(inp, XT_lds, j0, t);

  // hoisted packed os for k = 8kq .. 8kq+7 (slot s <-> d = (s&3)+4hi+8*(s>>2))
  uint4 os_pk[8];
  {
    const unsigned short* osb = osB + ((size_t)bt * 64 + lane) * 8 + (size_t)(8 * kq) * 1024;
#pragma unroll
    for (int kk = 0; kk < 8; ++kk) os_pk[kk] = *(const uint4*)(osb + (size_t)kk * 1024);
  }

  float acc[4][16];
#pragma unroll
  for (int q = 0; q < 4; ++q)
#pragma unroll
    for (int s = 0; s < 16; ++s) acc[q][s] = 0.f;

  const unsigned short* waBase =
      WB + (size_t)j0 * 8192 + (b31 >> 4) * 256 + (b31 & 15) * 16 + 8 * hi + (size_t)kq * 2048;

  uint4 a_cur[4];
#pragma unroll
  for (int q = 0; q < 4; ++q) a_cur[q] = *(const uint4*)(waBase + q * 512);
  __syncthreads();   // XT_lds ready

  for (int jj = 0; jj < JCR; ++jj) {
    uint4 a_nxt[4];
    if (jj + 1 < JCR) {
#pragma unroll
      for (int q = 0; q < 4; ++q)
        a_nxt[q] = *(const uint4*)(waBase + (size_t)(jj + 1) * 8192 + q * 512);
    }
    const short8v xf = __builtin_bit_cast(short8v,
        *(const uint4*)&XT_lds[((size_t)jj * 64 + b) * 8 + 4 * hi]);

    f32x16 u[4];
#pragma unroll
    for (int q = 0; q < 4; ++q)
      u[q] = __builtin_amdgcn_mfma_f32_32x32x16_bf16(
          __builtin_bit_cast(short8v, a_cur[q]), xf, zero16(), 0, 0, 0);

    float ee[4], eo[4];
    float Sp = 0.f;
#pragma unroll
    for (int q = 0; q < 4; ++q) {
      const unsigned int* o0 = (const unsigned int*)&os_pk[2 * q];
      const unsigned int* o1 = (const unsigned int*)&os_pk[2 * q + 1];
      float pe = 0.f, po = 0.f;
#pragma unroll
      for (int s = 0; s < 8; ++s) {
        const unsigned int w0 = o0[s >> 1], w1 = o1[s >> 1];
        pe = fmaf(u[q][s], bf2f((s & 1) ? (w0 >> 16) : (w0 & 0xffffu)), pe);
        po = fmaf(u[q][8 + s], bf2f((s & 1) ? (w1 >> 16) : (w1 & 0xffffu)), po);
      }
      pe += __shfl_xor(pe, 32);      // partner hi-half -> full dot over d
      po += __shfl_xor(po, 32);
      // logits O(+-8): skip max-subtraction (shift-invariant; validated r1-r23)
      ee[q] = __expf(pe);
      eo[q] = __expf(po);
      Sp += ee[q] + eo[q];
    }
    // cross-wave S reduction over the 4 kq waves (same bt); dbuf on jj parity
    if (hi == 0) Sbuf[((jj & 1) * 8 + kq * 2 + bt) * 32 + b31] = Sp;
    __syncthreads();
    const int sb = (jj & 1) * 8;
    const float S = Sbuf[(sb + 0 * 2 + bt) * 32 + b31] + Sbuf[(sb + 1 * 2 + bt) * 32 + b31] +
                    Sbuf[(sb + 2 * 2 + bt) * 32 + b31] + Sbuf[(sb + 3 * 2 + bt) * 32 + b31];
    const float rS = __builtin_amdgcn_rcpf(S);
#pragma unroll
    for (int q = 0; q < 4; ++q) {
      const float ce = ee[q] * rS, co = eo[q] * rS;
#pragma unroll
      for (int s = 0; s < 8; ++s) {
        acc[q][s] = fmaf(ce, u[q][s], acc[q][s]);
        acc[q][8 + s] = fmaf(co, u[q][8 + s], acc[q][8 + s]);
      }
      if constexpr (MODE == 2) {
        if (hi == 0) {
          const int k0 = 8 * kq + 2 * q;
          c_lds[((k0)*64 + b) * 9 + jj] = ce;       // pad-9: conflict-free
          c_lds[((k0 + 1) * 64 + b) * 9 + jj] = co;
        }
      }
    }
#pragma unroll
    for (int q = 0; q < 4; ++q) a_cur[q] = a_nxt[q];
  }

  // spart store, bf16-packed d-pairs
#pragma unroll
  for (int q = 0; q < 4; ++q) {
    const int keven = 8 * kq + 2 * q;
    unsigned int* se = spart_pk + (((size_t)b * NCH + ch) * 32 + keven) * 8 + 2 * hi;
    *(uint2*)se = make_uint2(cvtpk(acc[q][0], acc[q][1]), cvtpk(acc[q][2], acc[q][3]));
    *(uint2*)(se + 4) = make_uint2(cvtpk(acc[q][4], acc[q][5]), cvtpk(acc[q][6], acc[q][7]));
    unsigned int* so = se + 8;
    *(uint2*)so = make_uint2(cvtpk(acc[q][8], acc[q][9]), cvtpk(acc[q][10], acc[q][11]));
    *(uint2*)(so + 4) =
        make_uint2(cvtpk(acc[q][12], acc[q][13]), cvtpk(acc[q][14], acc[q][15]));
  }

  if constexpr (MODE == 2) {
    __syncthreads();
    // c transpose out: row r = k*64+b; 8 j's contiguous at outp[b][k][16+j0..]
#pragma unroll
    for (int m = 0; m < 4; ++m) {
      const int r = m * 512 + t;
      const int k = r >> 6, bb = r & 63;
      const float* cr = &c_lds[r * 9];
      float* orow = outp + ((size_t)bb * K_ + k) * 2064 + 16 + j0;
      *(float4*)orow = make_float4(cr[0], cr[1], cr[2], cr[3]);
      *(float4*)(orow + 4) = make_float4(cr[4], cr[5], cr[6], cr[7]);
    }
  }
}

// ---------------- squash: reduce packed spart (depth NCH) -> s, squash -> o.
// Wave per (b,k). Lane: h = d-pair (d = 2h, 2h+1), pg = lane>>3 (8 p-groups).
__global__ __launch_bounds__(256) void k_squash(const unsigned int* __restrict__ spart_pk,
                                                float* __restrict__ osum,
                                                unsigned short* __restrict__ osB,
                                                float* __restrict__ outp,
                                                int first, int final_) {
  const int t = threadIdx.x;
  const int wave = t >> 6, lane = t & 63;
  const int gw = blockIdx.x * 4 + wave;   // 0..B_*K_-1
  const int b = gw >> 5, k = gw & 31;
  const int h = lane & 7, pg = lane >> 3;
  float s0 = 0.f, s1 = 0.f;
#pragma unroll 8
  for (int p = pg; p < NCH; p += 8) {
    const unsigned int v = spart_pk[(((size_t)b * NCH + p) * 32 + k) * 8 + h];
    s0 += bf2f(v & 0xffffu);
    s1 += bf2f(v >> 16);
  }
  s0 += __shfl_xor(s0, 8);  s1 += __shfl_xor(s1, 8);
  s0 += __shfl_xor(s0, 16); s1 += __shfl_xor(s1, 16);
  s0 += __shfl_xor(s0, 32); s1 += __shfl_xor(s1, 32);
  float ss = s0 * s0 + s1 * s1;
  ss += __shfl_xor(ss, 1); ss += __shfl_xor(ss, 2); ss += __shfl_xor(ss, 4);
  const float scale = (ss / (1.f + ss)) * rsqrtf(ss + 1e-7f);
  const float ov0 = scale * s0, ov1 = scale * s1;
  if (final_) {
    if (pg == 0)
      *(float2*)(outp + ((size_t)b * K_ + k) * 2064 + 2 * h) = make_float2(ov0, ov1);
  } else {
    if (pg == 0) {
      float2 prev = make_float2(0.f, 0.f);
      if (!first) prev = *(const float2*)(osum + b * KD + k * 16 + 2 * h);
      const float ns0 = prev.x + ov0, ns1 = prev.y + ov1;
      *(float2*)(osum + b * KD + k * 16 + 2 * h) = make_float2(ns0, ns1);
      const int d0 = 2 * h;
      const int hi0 = (d0 >> 2) & 1;
      const int slot0 = (d0 & 3) + ((d0 >> 3) << 2);
      *(unsigned int*)(osB + (((size_t)k * 2 + (b >> 5)) * 64 + hi0 * 32 + (b & 31)) * 8 +
                       slot0) = cvtpk(ns0, ns1);
    }
  }
}

extern "C" void kernel_launch(void* const* d_in, const int* in_sizes, int n_in,
                              void* d_out, int out_size, void* d_ws, size_t ws_size,
                              hipStream_t stream) {
  const float* inp = (const float*)d_in[0];   // [64,2048,16]
  const float* W   = (const float*)d_in[1];   // [32,2048,16,16]
  float* outp = (float*)d_out;                // [64,32,2064]
  char* ws = (char*)d_ws;
  // ws: WB 32M @0 | spart_pk 16M @32M | osum 128K @48M | osB 64K
  unsigned short* WB = (unsigned short*)ws;
  unsigned int* spart_pk = (unsigned int*)(ws + (size_t)33554432);
  float* osum = (float*)(ws + (size_t)33554432 + 16777216);
  unsigned short* osB = (unsigned short*)(ws + (size_t)33554432 + 16777216 + 131072);

  // iter 0: c = 1/32, fused with x->LDS conversion and W->bf16 (writes WB)
  k_R0W<<<NCH, 512, 0, stream>>>(inp, W, WB, spart_pk);
  k_squash<<<B_ * K_ / 4, 256, 0, stream>>>(spart_pk, osum, osB, outp, 1, 0);
  // iter 1
  k_R<1><<<NCH, 512, 0, stream>>>(inp, WB, osB, spart_pk, nullptr);
  k_squash<<<B_ * K_ / 4, 256, 0, stream>>>(spart_pk, osum, osB, outp, 0, 0);
  // iter 2 (final): c -> outp via LDS transpose
  k_R<2><<<NCH, 512, 0, stream>>>(inp, WB, osB, spart_pk, outp);
  k_squash<<<B_ * K_ / 4, 256, 0, stream>>>(spart_pk, osum, osB, outp, 0, 1);
}